// Round 1
// baseline (2206.466 us; speedup 1.0000x reference)
//
#include <hip/hip_runtime.h>

#define C_IN  128
#define C_HID 128
#define C_OUT 64

// ---------------- degree / norm ----------------

__global__ __launch_bounds__(256) void k_deg_init(float* deg, int n) {
    int i = blockIdx.x * 256 + threadIdx.x;
    if (i < n) deg[i] = 1.0f;  // self-loop contributes 1 to every node's degree
}

__global__ __launch_bounds__(256) void k_deg_count(const int* __restrict__ ei, float* deg, int E) {
    int e = blockIdx.x * 256 + threadIdx.x;
    if (e < E) atomicAdd(&deg[ei[E + e]], 1.0f);  // dst row of edge_index
}

__global__ __launch_bounds__(256) void k_dinv(const float* __restrict__ deg, float* dinv, int n) {
    int i = blockIdx.x * 256 + threadIdx.x;
    if (i < n) dinv[i] = rsqrtf(deg[i]);  // deg >= 1 always (self-loop)
}

// ---------------- GEMM: H[M,N] = f(X)[M,128] @ W[128,N] ----------------
// f(X) = relu(X + bias) when RELU_BIAS, else X.
// Block: 256 threads, 64 rows of X staged in LDS (32KB), W streamed via L1/L2.
// Each thread: 1 output column x 8 rows (register accumulators).

template<int N, bool RELU_BIAS>
__global__ __launch_bounds__(256) void k_gemm(const float* __restrict__ X,
                                              const float* __restrict__ W,
                                              const float* __restrict__ bias,
                                              float* __restrict__ H, int M) {
    constexpr int K = 128;
    constexpr int ROWS = 64;
    __shared__ float sX[ROWS * K];  // 32 KiB

    const int tid = threadIdx.x;
    const int rowBase = blockIdx.x * ROWS;
    const float4* X4 = (const float4*)X;

    // stage 64 rows (2048 float4, 8 per thread), fusing relu(x+b) if requested
    #pragma unroll
    for (int i = 0; i < 8; ++i) {
        int idx = tid + 256 * i;
        int r = idx >> 5, c = idx & 31;    // 32 float4 per row
        int gr = rowBase + r;
        float4 v = make_float4(0.f, 0.f, 0.f, 0.f);
        if (gr < M) v = X4[(size_t)gr * 32 + c];
        if (RELU_BIAS) {
            float4 bv = ((const float4*)bias)[c];
            v.x = fmaxf(v.x + bv.x, 0.f);
            v.y = fmaxf(v.y + bv.y, 0.f);
            v.z = fmaxf(v.z + bv.z, 0.f);
            v.w = fmaxf(v.w + bv.w, 0.f);
        }
        ((float4*)sX)[idx] = v;
    }
    __syncthreads();

    constexpr int GROUPS = 256 / N;     // 2 (N=128) or 4 (N=64)
    constexpr int RT = 8;               // rows per thread
    constexpr int RPP = GROUPS * RT;    // rows per pass
    const int j = tid % N;              // output column
    const int g = tid / N;              // row group

    #pragma unroll
    for (int pass = 0; pass < ROWS / RPP; ++pass) {
        const int r0 = pass * RPP + g * RT;
        float acc[RT];
        #pragma unroll
        for (int r = 0; r < RT; ++r) acc[r] = 0.f;
        #pragma unroll 16
        for (int k = 0; k < K; ++k) {
            float w = W[k * N + j];     // coalesced across j; LDS reads are wave-broadcast
            #pragma unroll
            for (int r = 0; r < RT; ++r) acc[r] += sX[(r0 + r) * K + k] * w;
        }
        #pragma unroll
        for (int r = 0; r < RT; ++r) {
            int gr = rowBase + r0 + r;
            if (gr < M) H[(size_t)gr * N + j] = acc[r];
        }
    }
}

// ---------------- self-loop init: agg[v] = h[v]*dinv[v]^2 (+ bias) ----------------

template<int C, bool BIAS>
__global__ __launch_bounds__(256) void k_selfloop(const float* __restrict__ h,
                                                  const float* __restrict__ dinv,
                                                  const float* __restrict__ bias,
                                                  float* __restrict__ agg, int n) {
    int i = blockIdx.x * 256 + threadIdx.x;
    if (i >= n) return;
    int v = i / C;
    float di = dinv[v];
    float val = h[i] * di * di;
    if (BIAS) val += bias[i % C];
    agg[i] = val;
}

// ---------------- edge scatter: agg[dst] += h[src] * dinv[src]*dinv[dst] ----------------
// C/4 threads per edge, float4 gather, 4 scalar atomics per thread.

template<int C>
__global__ __launch_bounds__(256) void k_scatter(const float* __restrict__ h,
                                                 const int* __restrict__ ei,
                                                 const float* __restrict__ dinv,
                                                 float* __restrict__ agg, int E) {
    constexpr int TPE = C / 4;                  // threads per edge
    constexpr int SH = (C == 128) ? 5 : 4;
    int gid = blockIdx.x * 256 + threadIdx.x;
    int e = gid >> SH;
    if (e >= E) return;
    int part = gid & (TPE - 1);
    int s = ei[e];
    int d = ei[E + e];
    float c = dinv[s] * dinv[d];
    float4 v = ((const float4*)(h + (size_t)s * C))[part];
    float* out = agg + (size_t)d * C + part * 4;
    atomicAdd(out + 0, v.x * c);
    atomicAdd(out + 1, v.y * c);
    atomicAdd(out + 2, v.z * c);
    atomicAdd(out + 3, v.w * c);
}

// ---------------- launch ----------------

extern "C" void kernel_launch(void* const* d_in, const int* in_sizes, int n_in,
                              void* d_out, int out_size, void* d_ws, size_t ws_size,
                              hipStream_t stream) {
    const float* x  = (const float*)d_in[0];
    const int*   ei = (const int*)d_in[1];   // [2, E] row-major, int32
    const float* W1 = (const float*)d_in[2];
    const float* b1 = (const float*)d_in[3];
    const float* W2 = (const float*)d_in[4];
    const float* b2 = (const float*)d_in[5];
    float* out = (float*)d_out;

    const int N = in_sizes[0] / C_IN;   // 50000
    const int E = in_sizes[1] / 2;      // 800000

    // workspace layout (floats): deg[N] | dinv[N] | h[N*128] | agg1[N*128]
    float* deg  = (float*)d_ws;
    float* dinv = deg + N;
    float* h    = dinv + N;
    float* agg1 = h + (size_t)N * C_HID;
    float* h2   = h;  // reuse: layer-1 h dead once agg1 is complete

    dim3 blk(256);

    k_deg_init <<<(N + 255) / 256, blk, 0, stream>>>(deg, N);
    k_deg_count<<<(E + 255) / 256, blk, 0, stream>>>(ei, deg, E);
    k_dinv     <<<(N + 255) / 256, blk, 0, stream>>>(deg, dinv, N);

    const int gblocks = (N + 63) / 64;

    // layer 1: h = x @ W1 ; agg1 = Â h (self-loop init + edge scatter)
    k_gemm<C_HID, false><<<gblocks, blk, 0, stream>>>(x, W1, nullptr, h, N);
    k_selfloop<C_HID, false><<<((size_t)N * C_HID + 255) / 256, blk, 0, stream>>>(h, dinv, nullptr, agg1, N * C_HID);
    k_scatter<C_HID><<<((size_t)E * (C_HID / 4) + 255) / 256, blk, 0, stream>>>(h, ei, dinv, agg1, E);

    // layer 2: h2 = relu(agg1 + b1) @ W2 ; out = Â h2 + b2
    k_gemm<C_OUT, true><<<gblocks, blk, 0, stream>>>(agg1, W2, b1, h2, N);
    k_selfloop<C_OUT, true><<<((size_t)N * C_OUT + 255) / 256, blk, 0, stream>>>(h2, dinv, b2, out, N * C_OUT);
    k_scatter<C_OUT><<<((size_t)E * (C_OUT / 4) + 255) / 256, blk, 0, stream>>>(h2, ei, dinv, out, E);
}

// Round 2
// 362.695 us; speedup vs baseline: 6.0835x; 6.0835x over previous
//
#include <hip/hip_runtime.h>

#define C_IN  128
#define C_HID 128
#define C_OUT 64

// ================= CSR build =================

__global__ __launch_bounds__(256) void k_count(const int* __restrict__ ei, int* __restrict__ cnt, int E) {
    int e = blockIdx.x * 256 + threadIdx.x;
    if (e < E) atomicAdd(&cnt[ei[E + e]], 1);  // dst
}

__global__ __launch_bounds__(256) void k_dinv(const int* __restrict__ cnt, float* __restrict__ dinv, int n) {
    int i = blockIdx.x * 256 + threadIdx.x;
    if (i < n) dinv[i] = rsqrtf((float)(cnt[i] + 1));  // +1 self-loop
}

// Exclusive scan of cnt[n] -> row_ptr, 256 elems/block.
__global__ __launch_bounds__(256) void k_scan1(const int* __restrict__ cnt, int* __restrict__ row_ptr,
                                               int* __restrict__ bsum, int n) {
    __shared__ int s[256];
    int tid = threadIdx.x;
    int i = blockIdx.x * 256 + tid;
    int v = (i < n) ? cnt[i] : 0;
    s[tid] = v;
    __syncthreads();
    #pragma unroll
    for (int off = 1; off < 256; off <<= 1) {
        int t = (tid >= off) ? s[tid - off] : 0;
        __syncthreads();
        s[tid] += t;
        __syncthreads();
    }
    if (i < n) row_ptr[i] = s[tid] - v;       // exclusive, local
    if (tid == 255) bsum[blockIdx.x] = s[255];
}

__global__ __launch_bounds__(256) void k_scan2(const int* __restrict__ bsum, int* __restrict__ bpre, int nb) {
    __shared__ int s[256];
    int tid = threadIdx.x;
    int v = (tid < nb) ? bsum[tid] : 0;
    s[tid] = v;
    __syncthreads();
    #pragma unroll
    for (int off = 1; off < 256; off <<= 1) {
        int t = (tid >= off) ? s[tid - off] : 0;
        __syncthreads();
        s[tid] += t;
        __syncthreads();
    }
    if (tid < nb) bpre[tid] = s[tid] - v;     // exclusive
}

__global__ __launch_bounds__(256) void k_scan3(int* __restrict__ row_ptr, int* __restrict__ cursor,
                                               const int* __restrict__ bpre, int n, int E) {
    int i = blockIdx.x * 256 + threadIdx.x;
    if (i < n) {
        int r = row_ptr[i] + bpre[blockIdx.x];
        row_ptr[i] = r;
        cursor[i] = r;
    }
    if (i == 0) row_ptr[n] = E;
}

__global__ __launch_bounds__(256) void k_fill(const int* __restrict__ ei, const float* __restrict__ dinv,
                                              int* __restrict__ cursor, int* __restrict__ csr_src,
                                              float* __restrict__ csr_coef, int E) {
    int e = blockIdx.x * 256 + threadIdx.x;
    if (e >= E) return;
    int s = ei[e];
    int d = ei[E + e];
    int pos = atomicAdd(&cursor[d], 1);
    csr_src[pos] = s;
    csr_coef[pos] = dinv[s] * dinv[d];
}

// ================= GEMM: H[M,N] = f(X)[M,128] @ W[128,N] =================
// f = relu(x + b1) when RELU_BIAS. 64 rows staged in LDS, 8 rows x 1 col per thread.

template<int N, bool RELU_BIAS>
__global__ __launch_bounds__(256) void k_gemm(const float* __restrict__ X,
                                              const float* __restrict__ W,
                                              const float* __restrict__ bias,
                                              float* __restrict__ H, int M) {
    constexpr int K = 128;
    constexpr int ROWS = 64;
    __shared__ float sX[ROWS * K];

    const int tid = threadIdx.x;
    const int rowBase = blockIdx.x * ROWS;
    const float4* X4 = (const float4*)X;

    #pragma unroll
    for (int i = 0; i < 8; ++i) {
        int idx = tid + 256 * i;
        int r = idx >> 5, c = idx & 31;
        int gr = rowBase + r;
        float4 v = make_float4(0.f, 0.f, 0.f, 0.f);
        if (gr < M) v = X4[(size_t)gr * 32 + c];
        if (RELU_BIAS) {
            float4 bv = ((const float4*)bias)[c];
            v.x = fmaxf(v.x + bv.x, 0.f);
            v.y = fmaxf(v.y + bv.y, 0.f);
            v.z = fmaxf(v.z + bv.z, 0.f);
            v.w = fmaxf(v.w + bv.w, 0.f);
        }
        ((float4*)sX)[idx] = v;
    }
    __syncthreads();

    constexpr int GROUPS = 256 / N;
    constexpr int RT = 8;
    constexpr int RPP = GROUPS * RT;
    const int j = tid % N;
    const int g = tid / N;

    #pragma unroll
    for (int pass = 0; pass < ROWS / RPP; ++pass) {
        const int r0 = pass * RPP + g * RT;
        float acc[RT];
        #pragma unroll
        for (int r = 0; r < RT; ++r) acc[r] = 0.f;
        #pragma unroll 16
        for (int k = 0; k < K; ++k) {
            float w = W[k * N + j];
            #pragma unroll
            for (int r = 0; r < RT; ++r) acc[r] += sX[(r0 + r) * K + k] * w;
        }
        #pragma unroll
        for (int r = 0; r < RT; ++r) {
            int gr = rowBase + r0 + r;
            if (gr < M) H[(size_t)gr * N + j] = acc[r];
        }
    }
}

// ================= aggregation: one wave per node, gather-side =================
// agg[v] = h[v]*dinv[v]^2 + sum_{s in N(v)} coef * h[s]   (+ bias)

template<int C, bool BIAS>
__global__ __launch_bounds__(256) void k_aggregate(const float* __restrict__ h,
                                                   const int* __restrict__ row_ptr,
                                                   const int* __restrict__ csr_src,
                                                   const float* __restrict__ csr_coef,
                                                   const float* __restrict__ dinv,
                                                   const float* __restrict__ bias,
                                                   float* __restrict__ agg, int n) {
    constexpr int VPC = C / 64;                 // floats per lane: 2 (C=128) or 1 (C=64)
    const int lane = threadIdx.x & 63;
    const int v = blockIdx.x * 4 + (threadIdx.x >> 6);
    if (v >= n) return;

    float acc[VPC];
    {
        float di = dinv[v];
        float sl = di * di;
        #pragma unroll
        for (int u = 0; u < VPC; ++u)
            acc[u] = h[(size_t)v * C + lane * VPC + u] * sl;
    }

    const int e0 = row_ptr[v], e1 = row_ptr[v + 1];
    for (int base = e0; base < e1; base += 64) {
        const int m = min(64, e1 - base);
        int   myS = 0;
        float myC = 0.f;
        if (lane < m) {
            myS = csr_src[base + lane];
            myC = csr_coef[base + lane];
        }
        for (int j = 0; j < m; ++j) {
            int   s = __shfl(myS, j);
            float c = __shfl(myC, j);
            if (VPC == 2) {
                float2 hv = ((const float2*)(h + (size_t)s * C))[lane];
                acc[0] += c * hv.x;
                acc[1] += c * hv.y;
            } else {
                acc[0] += c * h[(size_t)s * C + lane];
            }
        }
    }

    #pragma unroll
    for (int u = 0; u < VPC; ++u) {
        float val = acc[u];
        if (BIAS) val += bias[lane * VPC + u];
        agg[(size_t)v * C + lane * VPC + u] = val;
    }
}

// ================= launch =================

extern "C" void kernel_launch(void* const* d_in, const int* in_sizes, int n_in,
                              void* d_out, int out_size, void* d_ws, size_t ws_size,
                              hipStream_t stream) {
    const float* x  = (const float*)d_in[0];
    const int*   ei = (const int*)d_in[1];
    const float* W1 = (const float*)d_in[2];
    const float* b1 = (const float*)d_in[3];
    const float* W2 = (const float*)d_in[4];
    const float* b2 = (const float*)d_in[5];
    float* out = (float*)d_out;

    const int N = in_sizes[0] / C_IN;   // 50000
    const int E = in_sizes[1] / 2;      // 800000

    // workspace layout
    char* p = (char*)d_ws;
    int*   cnt      = (int*)p;                 p += (size_t)N * 4;
    float* dinv     = (float*)p;               p += (size_t)N * 4;
    int*   row_ptr  = (int*)p;                 p += (size_t)(N + 1) * 4;
    int*   cursor   = (int*)p;                 p += (size_t)N * 4;
    int*   bsum     = (int*)p;                 p += 256 * 4;
    int*   bpre     = (int*)p;                 p += 256 * 4;
    int*   csr_src  = (int*)p;                 p += (size_t)E * 4;
    float* csr_coef = (float*)p;               p += (size_t)E * 4;
    float* h        = (float*)p;               p += (size_t)N * C_HID * 4;
    float* agg1     = (float*)p;               p += (size_t)N * C_HID * 4;
    float* h2       = h;  // reuse

    dim3 blk(256);
    const int nbS = (N + 255) / 256;           // 196 scan blocks

    hipMemsetAsync(cnt, 0, (size_t)N * 4, stream);
    k_count<<<(E + 255) / 256, blk, 0, stream>>>(ei, cnt, E);
    k_dinv <<<nbS, blk, 0, stream>>>(cnt, dinv, N);
    k_scan1<<<nbS, blk, 0, stream>>>(cnt, row_ptr, bsum, N);
    k_scan2<<<1, blk, 0, stream>>>(bsum, bpre, nbS);
    k_scan3<<<nbS, blk, 0, stream>>>(row_ptr, cursor, bpre, N, E);
    k_fill <<<(E + 255) / 256, blk, 0, stream>>>(ei, dinv, cursor, csr_src, csr_coef, E);

    const int gblocks = (N + 63) / 64;
    const int ablocks = (N + 3) / 4;

    // layer 1
    k_gemm<C_HID, false><<<gblocks, blk, 0, stream>>>(x, W1, nullptr, h, N);
    k_aggregate<C_HID, false><<<ablocks, blk, 0, stream>>>(h, row_ptr, csr_src, csr_coef, dinv, nullptr, agg1, N);

    // layer 2
    k_gemm<C_OUT, true><<<gblocks, blk, 0, stream>>>(agg1, W2, b1, h2, N);
    k_aggregate<C_OUT, true><<<ablocks, blk, 0, stream>>>(h2, row_ptr, csr_src, csr_coef, dinv, b2, out, N);
}

// Round 3
// 337.737 us; speedup vs baseline: 6.5331x; 1.0739x over previous
//
#include <hip/hip_runtime.h>

#define C_IN  128
#define C_HID 128
#define C_OUT 64

// ================= CSR build =================

__global__ __launch_bounds__(256) void k_count(const int* __restrict__ ei, int* __restrict__ cnt, int E) {
    int e = blockIdx.x * 256 + threadIdx.x;
    if (e < E) atomicAdd(&cnt[ei[E + e]], 1);  // dst
}

__global__ __launch_bounds__(256) void k_dinv(const int* __restrict__ cnt, float* __restrict__ dinv, int n) {
    int i = blockIdx.x * 256 + threadIdx.x;
    if (i < n) dinv[i] = rsqrtf((float)(cnt[i] + 1));  // +1 self-loop
}

// Exclusive scan of cnt[n] -> row_ptr, 256 elems/block.
__global__ __launch_bounds__(256) void k_scan1(const int* __restrict__ cnt, int* __restrict__ row_ptr,
                                               int* __restrict__ bsum, int n) {
    __shared__ int s[256];
    int tid = threadIdx.x;
    int i = blockIdx.x * 256 + tid;
    int v = (i < n) ? cnt[i] : 0;
    s[tid] = v;
    __syncthreads();
    #pragma unroll
    for (int off = 1; off < 256; off <<= 1) {
        int t = (tid >= off) ? s[tid - off] : 0;
        __syncthreads();
        s[tid] += t;
        __syncthreads();
    }
    if (i < n) row_ptr[i] = s[tid] - v;       // exclusive, local
    if (tid == 255) bsum[blockIdx.x] = s[255];
}

__global__ __launch_bounds__(256) void k_scan2(const int* __restrict__ bsum, int* __restrict__ bpre, int nb) {
    __shared__ int s[256];
    int tid = threadIdx.x;
    int v = (tid < nb) ? bsum[tid] : 0;
    s[tid] = v;
    __syncthreads();
    #pragma unroll
    for (int off = 1; off < 256; off <<= 1) {
        int t = (tid >= off) ? s[tid - off] : 0;
        __syncthreads();
        s[tid] += t;
        __syncthreads();
    }
    if (tid < nb) bpre[tid] = s[tid] - v;     // exclusive
}

__global__ __launch_bounds__(256) void k_scan3(int* __restrict__ row_ptr, int* __restrict__ cursor,
                                               const int* __restrict__ bpre, int n, int E) {
    int i = blockIdx.x * 256 + threadIdx.x;
    if (i < n) {
        int r = row_ptr[i] + bpre[blockIdx.x];
        row_ptr[i] = r;
        cursor[i] = r;
    }
    if (i == 0) row_ptr[n] = E;
}

__global__ __launch_bounds__(256) void k_fill(const int* __restrict__ ei, const float* __restrict__ dinv,
                                              int* __restrict__ cursor, int* __restrict__ csr_src,
                                              float* __restrict__ csr_coef, int E) {
    int e = blockIdx.x * 256 + threadIdx.x;
    if (e >= E) return;
    int s = ei[e];
    int d = ei[E + e];
    int pos = atomicAdd(&cursor[d], 1);
    csr_src[pos] = s;
    csr_coef[pos] = dinv[s] * dinv[d];
}

// ================= GEMM: H[M,N] = X[M,128] @ W[128,N] =================
// Lanes = output columns (col j = lane [+64]); rows are wave-uniform.
// X[m][k] has a uniform address -> s_load into SGPRs (free FMA operand).
// W staged in LDS; per k: CPL ds_read_b32 (conflict-free) + 8*CPL FMAs.

template<int N, int BM>
__global__ __launch_bounds__(256) void k_gemm(const float* __restrict__ X,
                                              const float* __restrict__ W,
                                              float* __restrict__ H, int M) {
    constexpr int K = 128;
    __shared__ float sW[K * N];                 // 64 KB (N=128) / 32 KB (N=64)

    const int tid = threadIdx.x;
    // stage W (coalesced float4)
    {
        constexpr int WTOT4 = K * N / 4;
        const float4* W4 = (const float4*)W;
        #pragma unroll
        for (int i = tid; i < WTOT4; i += 256) ((float4*)sW)[i] = W4[i];
    }
    __syncthreads();

    const int wave = __builtin_amdgcn_readfirstlane(tid >> 6);  // wave-uniform in SGPR
    const int lane = tid & 63;
    const int rowBase = blockIdx.x * BM;

    constexpr int CPL = N / 64;                 // cols per lane: 2 (N=128) or 1 (N=64)
    constexpr int R = 8;                        // rows per wave per chunk

    for (int c0 = 0; c0 < BM; c0 += 4 * R) {
        const int m0 = rowBase + c0 + wave * R;
        if (m0 >= M) continue;

        float acc[R][CPL];
        #pragma unroll
        for (int r = 0; r < R; ++r)
            #pragma unroll
            for (int u = 0; u < CPL; ++u) acc[r][u] = 0.f;

        const float* Xb = X + (size_t)m0 * K;
        const bool full = (m0 + R <= M);

        if (full) {
            #pragma unroll 2
            for (int k0 = 0; k0 < K; k0 += 4) {
                float4 xv[R];
                #pragma unroll
                for (int r = 0; r < R; ++r)
                    xv[r] = *(const float4*)(Xb + (size_t)r * K + k0);  // uniform -> s_load
                #pragma unroll
                for (int kk = 0; kk < 4; ++kk) {
                    float w0 = sW[(k0 + kk) * N + lane];
                    float w1 = (CPL == 2) ? sW[(k0 + kk) * N + 64 + lane] : 0.f;
                    #pragma unroll
                    for (int r = 0; r < R; ++r) {
                        float xr = (kk == 0) ? xv[r].x : (kk == 1) ? xv[r].y
                                 : (kk == 2) ? xv[r].z : xv[r].w;
                        acc[r][0] += xr * w0;
                        if (CPL == 2) acc[r][1] += xr * w1;
                    }
                }
            }
            #pragma unroll
            for (int r = 0; r < R; ++r) {
                H[(size_t)(m0 + r) * N + lane] = acc[r][0];
                if (CPL == 2) H[(size_t)(m0 + r) * N + 64 + lane] = acc[r][1];
            }
        } else {
            // tail: per-row uniform guards
            for (int k0 = 0; k0 < K; k0 += 4) {
                float4 xv[R];
                #pragma unroll
                for (int r = 0; r < R; ++r) {
                    if (m0 + r < M) xv[r] = *(const float4*)(Xb + (size_t)r * K + k0);
                    else            xv[r] = make_float4(0.f, 0.f, 0.f, 0.f);
                }
                #pragma unroll
                for (int kk = 0; kk < 4; ++kk) {
                    float w0 = sW[(k0 + kk) * N + lane];
                    float w1 = (CPL == 2) ? sW[(k0 + kk) * N + 64 + lane] : 0.f;
                    #pragma unroll
                    for (int r = 0; r < R; ++r) {
                        float xr = (kk == 0) ? xv[r].x : (kk == 1) ? xv[r].y
                                 : (kk == 2) ? xv[r].z : xv[r].w;
                        acc[r][0] += xr * w0;
                        if (CPL == 2) acc[r][1] += xr * w1;
                    }
                }
            }
            #pragma unroll
            for (int r = 0; r < R; ++r) {
                if (m0 + r < M) {
                    H[(size_t)(m0 + r) * N + lane] = acc[r][0];
                    if (CPL == 2) H[(size_t)(m0 + r) * N + 64 + lane] = acc[r][1];
                }
            }
        }
    }
}

// ================= aggregation: one wave per node, gather-side =================
// agg[v] = f( h[v]*dinv[v]^2 + sum_{s in N(v)} coef*h[s] + bias )
// f = relu when RELU (layer-1 epilogue: relu(. + b1) fused here).

template<int C, bool BIAS, bool RELU>
__global__ __launch_bounds__(256) void k_aggregate(const float* __restrict__ h,
                                                   const int* __restrict__ row_ptr,
                                                   const int* __restrict__ csr_src,
                                                   const float* __restrict__ csr_coef,
                                                   const float* __restrict__ dinv,
                                                   const float* __restrict__ bias,
                                                   float* __restrict__ agg, int n) {
    constexpr int VPC = C / 64;
    const int lane = threadIdx.x & 63;
    const int v = blockIdx.x * 4 + (threadIdx.x >> 6);
    if (v >= n) return;

    float acc[VPC];
    {
        float di = dinv[v];
        float sl = di * di;
        #pragma unroll
        for (int u = 0; u < VPC; ++u)
            acc[u] = h[(size_t)v * C + lane * VPC + u] * sl;
    }

    const int e0 = row_ptr[v], e1 = row_ptr[v + 1];
    for (int base = e0; base < e1; base += 64) {
        const int m = min(64, e1 - base);
        int   myS = 0;
        float myC = 0.f;
        if (lane < m) {
            myS = csr_src[base + lane];
            myC = csr_coef[base + lane];
        }
        for (int j = 0; j < m; ++j) {
            int   s = __shfl(myS, j);
            float c = __shfl(myC, j);
            if (VPC == 2) {
                float2 hv = ((const float2*)(h + (size_t)s * C))[lane];
                acc[0] += c * hv.x;
                acc[1] += c * hv.y;
            } else {
                acc[0] += c * h[(size_t)s * C + lane];
            }
        }
    }

    #pragma unroll
    for (int u = 0; u < VPC; ++u) {
        float val = acc[u];
        if (BIAS) val += bias[lane * VPC + u];
        if (RELU) val = fmaxf(val, 0.f);
        agg[(size_t)v * C + lane * VPC + u] = val;
    }
}

// ================= launch =================

extern "C" void kernel_launch(void* const* d_in, const int* in_sizes, int n_in,
                              void* d_out, int out_size, void* d_ws, size_t ws_size,
                              hipStream_t stream) {
    const float* x  = (const float*)d_in[0];
    const int*   ei = (const int*)d_in[1];
    const float* W1 = (const float*)d_in[2];
    const float* b1 = (const float*)d_in[3];
    const float* W2 = (const float*)d_in[4];
    const float* b2 = (const float*)d_in[5];
    float* out = (float*)d_out;

    const int N = in_sizes[0] / C_IN;   // 50000
    const int E = in_sizes[1] / 2;      // 800000

    // workspace layout
    char* p = (char*)d_ws;
    int*   cnt      = (int*)p;                 p += (size_t)N * 4;
    float* dinv     = (float*)p;               p += (size_t)N * 4;
    int*   row_ptr  = (int*)p;                 p += (size_t)(N + 1) * 4;
    int*   cursor   = (int*)p;                 p += (size_t)N * 4;
    int*   bsum     = (int*)p;                 p += 256 * 4;
    int*   bpre     = (int*)p;                 p += 256 * 4;
    int*   csr_src  = (int*)p;                 p += (size_t)E * 4;
    float* csr_coef = (float*)p;               p += (size_t)E * 4;
    float* h        = (float*)p;               p += (size_t)N * C_HID * 4;
    float* agg1     = (float*)p;               p += (size_t)N * C_HID * 4;
    float* h2       = h;  // reuse

    dim3 blk(256);
    const int nbS = (N + 255) / 256;

    hipMemsetAsync(cnt, 0, (size_t)N * 4, stream);
    k_count<<<(E + 255) / 256, blk, 0, stream>>>(ei, cnt, E);
    k_dinv <<<nbS, blk, 0, stream>>>(cnt, dinv, N);
    k_scan1<<<nbS, blk, 0, stream>>>(cnt, row_ptr, bsum, N);
    k_scan2<<<1, blk, 0, stream>>>(bsum, bpre, nbS);
    k_scan3<<<nbS, blk, 0, stream>>>(row_ptr, cursor, bpre, N, E);
    k_fill <<<(E + 255) / 256, blk, 0, stream>>>(ei, dinv, cursor, csr_src, csr_coef, E);

    constexpr int BM = 64;
    const int gblocks = (N + BM - 1) / BM;
    const int ablocks = (N + 3) / 4;

    // layer 1: h = x@W1 ; agg1 = relu(Â h + b1)
    k_gemm<C_HID, BM><<<gblocks, blk, 0, stream>>>(x, W1, h, N);
    k_aggregate<C_HID, true, true><<<ablocks, blk, 0, stream>>>(h, row_ptr, csr_src, csr_coef, dinv, b1, agg1, N);

    // layer 2: h2 = agg1@W2 ; out = Â h2 + b2
    k_gemm<C_OUT, BM><<<gblocks, blk, 0, stream>>>(agg1, W2, h2, N);
    k_aggregate<C_OUT, true, false><<<ablocks, blk, 0, stream>>>(h2, row_ptr, csr_src, csr_coef, dinv, b2, out, N);
}

// Round 5
// 302.700 us; speedup vs baseline: 7.2893x; 1.1157x over previous
//
#include <hip/hip_runtime.h>

#define C_IN  128
#define C_HID 128
#define C_OUT 64

// ================= CSR build =================

__global__ __launch_bounds__(256) void k_count(const int* __restrict__ ei, int* __restrict__ cnt, int E) {
    int e = blockIdx.x * 256 + threadIdx.x;
    if (e < E) atomicAdd(&cnt[ei[E + e]], 1);  // dst
}

__global__ __launch_bounds__(256) void k_dinv(const int* __restrict__ cnt, float* __restrict__ dinv, int n) {
    int i = blockIdx.x * 256 + threadIdx.x;
    if (i < n) dinv[i] = rsqrtf((float)(cnt[i] + 1));  // +1 self-loop
}

__global__ __launch_bounds__(256) void k_scan1(const int* __restrict__ cnt, int* __restrict__ row_ptr,
                                               int* __restrict__ bsum, int n) {
    __shared__ int s[256];
    int tid = threadIdx.x;
    int i = blockIdx.x * 256 + tid;
    int v = (i < n) ? cnt[i] : 0;
    s[tid] = v;
    __syncthreads();
    #pragma unroll
    for (int off = 1; off < 256; off <<= 1) {
        int t = (tid >= off) ? s[tid - off] : 0;
        __syncthreads();
        s[tid] += t;
        __syncthreads();
    }
    if (i < n) row_ptr[i] = s[tid] - v;
    if (tid == 255) bsum[blockIdx.x] = s[255];
}

__global__ __launch_bounds__(256) void k_scan2(const int* __restrict__ bsum, int* __restrict__ bpre, int nb) {
    __shared__ int s[256];
    int tid = threadIdx.x;
    int v = (tid < nb) ? bsum[tid] : 0;
    s[tid] = v;
    __syncthreads();
    #pragma unroll
    for (int off = 1; off < 256; off <<= 1) {
        int t = (tid >= off) ? s[tid - off] : 0;
        __syncthreads();
        s[tid] += t;
        __syncthreads();
    }
    if (tid < nb) bpre[tid] = s[tid] - v;
}

__global__ __launch_bounds__(256) void k_scan3(int* __restrict__ row_ptr, int* __restrict__ cursor,
                                               const int* __restrict__ bpre, int n, int E) {
    int i = blockIdx.x * 256 + threadIdx.x;
    if (i < n) {
        int r = row_ptr[i] + bpre[blockIdx.x];
        row_ptr[i] = r;
        cursor[i] = r;
    }
    if (i == 0) row_ptr[n] = E;
}

__global__ __launch_bounds__(256) void k_fill(const int* __restrict__ ei, const float* __restrict__ dinv,
                                              int* __restrict__ cursor, int2* __restrict__ csr, int E) {
    int e = blockIdx.x * 256 + threadIdx.x;
    if (e >= E) return;
    int s = ei[e];
    int d = ei[E + e];
    int pos = atomicAdd(&cursor[d], 1);
    csr[pos] = make_int2(s, __float_as_int(dinv[s] * dinv[d]));
}

// ================= GEMM: H[M,N] = X[M,128] @ W[128,N] (R3-proven) =================

template<int N, int BM>
__global__ __launch_bounds__(256) void k_gemm(const float* __restrict__ X,
                                              const float* __restrict__ W,
                                              float* __restrict__ H, int M) {
    constexpr int K = 128;
    __shared__ float sW[K * N];

    const int tid = threadIdx.x;
    {
        constexpr int WTOT4 = K * N / 4;
        const float4* W4 = (const float4*)W;
        #pragma unroll
        for (int i = tid; i < WTOT4; i += 256) ((float4*)sW)[i] = W4[i];
    }
    __syncthreads();

    const int wave = __builtin_amdgcn_readfirstlane(tid >> 6);
    const int lane = tid & 63;
    const int rowBase = blockIdx.x * BM;

    constexpr int CPL = N / 64;
    constexpr int R = 8;

    for (int c0 = 0; c0 < BM; c0 += 4 * R) {
        const int m0 = rowBase + c0 + wave * R;
        if (m0 >= M) continue;

        float acc[R][CPL];
        #pragma unroll
        for (int r = 0; r < R; ++r)
            #pragma unroll
            for (int u = 0; u < CPL; ++u) acc[r][u] = 0.f;

        const float* Xb = X + (size_t)m0 * K;
        const bool full = (m0 + R <= M);

        if (full) {
            #pragma unroll 2
            for (int k0 = 0; k0 < K; k0 += 4) {
                float4 xv[R];
                #pragma unroll
                for (int r = 0; r < R; ++r)
                    xv[r] = *(const float4*)(Xb + (size_t)r * K + k0);
                #pragma unroll
                for (int kk = 0; kk < 4; ++kk) {
                    float w0 = sW[(k0 + kk) * N + lane];
                    float w1 = (CPL == 2) ? sW[(k0 + kk) * N + 64 + lane] : 0.f;
                    #pragma unroll
                    for (int r = 0; r < R; ++r) {
                        float xr = (kk == 0) ? xv[r].x : (kk == 1) ? xv[r].y
                                 : (kk == 2) ? xv[r].z : xv[r].w;
                        acc[r][0] += xr * w0;
                        if (CPL == 2) acc[r][1] += xr * w1;
                    }
                }
            }
            #pragma unroll
            for (int r = 0; r < R; ++r) {
                H[(size_t)(m0 + r) * N + lane] = acc[r][0];
                if (CPL == 2) H[(size_t)(m0 + r) * N + 64 + lane] = acc[r][1];
            }
        } else {
            for (int k0 = 0; k0 < K; k0 += 4) {
                float4 xv[R];
                #pragma unroll
                for (int r = 0; r < R; ++r) {
                    if (m0 + r < M) xv[r] = *(const float4*)(Xb + (size_t)r * K + k0);
                    else            xv[r] = make_float4(0.f, 0.f, 0.f, 0.f);
                }
                #pragma unroll
                for (int kk = 0; kk < 4; ++kk) {
                    float w0 = sW[(k0 + kk) * N + lane];
                    float w1 = (CPL == 2) ? sW[(k0 + kk) * N + 64 + lane] : 0.f;
                    #pragma unroll
                    for (int r = 0; r < R; ++r) {
                        float xr = (kk == 0) ? xv[r].x : (kk == 1) ? xv[r].y
                                 : (kk == 2) ? xv[r].z : xv[r].w;
                        acc[r][0] += xr * w0;
                        if (CPL == 2) acc[r][1] += xr * w1;
                    }
                }
            }
            #pragma unroll
            for (int r = 0; r < R; ++r) {
                if (m0 + r < M) {
                    H[(size_t)(m0 + r) * N + lane] = acc[r][0];
                    if (CPL == 2) H[(size_t)(m0 + r) * N + 64 + lane] = acc[r][1];
                }
            }
        }
    }
}

// ================= aggregation (R3 semantics: lane = fixed channels, sequential j) =================
// Wave-uniform node index (readfirstlane) -> CSR entries load as scalar loads;
// edge loop unrolled with loads hoisted -> U gathers in flight per wave.

template<bool RELU>
__global__ __launch_bounds__(256) void k_agg128(const float* __restrict__ h,
                                                const int* __restrict__ row_ptr,
                                                const int2* __restrict__ csr,
                                                const float* __restrict__ dinv,
                                                const float* __restrict__ bias,
                                                float* __restrict__ agg, int n) {
    const int lane = threadIdx.x & 63;
    int vt = blockIdx.x * 4 + (threadIdx.x >> 6);
    if (vt >= n) return;
    const int v = __builtin_amdgcn_readfirstlane(vt);

    const float2* h2 = (const float2*)h;
    float2 acc;
    {
        float di = dinv[v];
        float sl = di * di;
        float2 t = h2[(size_t)v * 64 + lane];
        acc.x = t.x * sl;
        acc.y = t.y * sl;
    }

    const int e0 = row_ptr[v], e1 = row_ptr[v + 1];
    int j = e0;
    constexpr int U = 4;
    for (; j + U <= e1; j += U) {
        int2   ee[U];
        float2 hv[U];
        #pragma unroll
        for (int u = 0; u < U; ++u) ee[u] = csr[j + u];         // scalar loads (uniform addr)
        #pragma unroll
        for (int u = 0; u < U; ++u) hv[u] = h2[(size_t)ee[u].x * 64 + lane];
        #pragma unroll
        for (int u = 0; u < U; ++u) {
            float c = __int_as_float(ee[u].y);
            acc.x += c * hv[u].x;
            acc.y += c * hv[u].y;
        }
    }
    for (; j < e1; ++j) {
        int2 e = csr[j];
        float c = __int_as_float(e.y);
        float2 t = h2[(size_t)e.x * 64 + lane];
        acc.x += c * t.x;
        acc.y += c * t.y;
    }

    {
        float2 bv = ((const float2*)bias)[lane];
        acc.x += bv.x;
        acc.y += bv.y;
        if (RELU) {
            acc.x = fmaxf(acc.x, 0.f);
            acc.y = fmaxf(acc.y, 0.f);
        }
        ((float2*)agg)[(size_t)v * 64 + lane] = acc;
    }
}

template<bool RELU>
__global__ __launch_bounds__(256) void k_agg64(const float* __restrict__ h,
                                               const int* __restrict__ row_ptr,
                                               const int2* __restrict__ csr,
                                               const float* __restrict__ dinv,
                                               const float* __restrict__ bias,
                                               float* __restrict__ agg, int n) {
    const int lane = threadIdx.x & 63;
    int vt = blockIdx.x * 4 + (threadIdx.x >> 6);
    if (vt >= n) return;
    const int v = __builtin_amdgcn_readfirstlane(vt);

    float acc;
    {
        float di = dinv[v];
        acc = h[(size_t)v * 64 + lane] * di * di;
    }

    const int e0 = row_ptr[v], e1 = row_ptr[v + 1];
    int j = e0;
    constexpr int U = 8;
    for (; j + U <= e1; j += U) {
        int2  ee[U];
        float hv[U];
        #pragma unroll
        for (int u = 0; u < U; ++u) ee[u] = csr[j + u];
        #pragma unroll
        for (int u = 0; u < U; ++u) hv[u] = h[(size_t)ee[u].x * 64 + lane];
        #pragma unroll
        for (int u = 0; u < U; ++u) acc += __int_as_float(ee[u].y) * hv[u];
    }
    for (; j < e1; ++j) {
        int2 e = csr[j];
        acc += __int_as_float(e.y) * h[(size_t)e.x * 64 + lane];
    }

    acc += bias[lane];
    if (RELU) acc = fmaxf(acc, 0.f);
    agg[(size_t)v * 64 + lane] = acc;
}

// ================= launch =================

extern "C" void kernel_launch(void* const* d_in, const int* in_sizes, int n_in,
                              void* d_out, int out_size, void* d_ws, size_t ws_size,
                              hipStream_t stream) {
    const float* x  = (const float*)d_in[0];
    const int*   ei = (const int*)d_in[1];
    const float* W1 = (const float*)d_in[2];
    const float* b1 = (const float*)d_in[3];
    const float* W2 = (const float*)d_in[4];
    const float* b2 = (const float*)d_in[5];
    float* out = (float*)d_out;

    const int N = in_sizes[0] / C_IN;   // 50000
    const int E = in_sizes[1] / 2;      // 800000

    // 16B-aligned workspace layout
    char* base = (char*)d_ws;
    size_t off = 0;
    auto alloc = [&](size_t bytes) {
        char* q = base + off;
        off = (off + bytes + 15) & ~(size_t)15;
        return q;
    };
    int*   cnt      = (int*)  alloc((size_t)N * 4);
    float* dinv     = (float*)alloc((size_t)N * 4);
    int*   row_ptr  = (int*)  alloc((size_t)(N + 1) * 4);
    int*   cursor   = (int*)  alloc((size_t)N * 4);
    int*   bsum     = (int*)  alloc(256 * 4);
    int*   bpre     = (int*)  alloc(256 * 4);
    int2*  csr      = (int2*) alloc((size_t)E * 8);
    float* h        = (float*)alloc((size_t)N * C_HID * 4);
    float* agg1     = (float*)alloc((size_t)N * C_HID * 4);
    float* h2       = h;  // reuse: layer-1 h dead once agg1 complete

    dim3 blk(256);
    const int nbS = (N + 255) / 256;

    hipMemsetAsync(cnt, 0, (size_t)N * 4, stream);
    k_count<<<(E + 255) / 256, blk, 0, stream>>>(ei, cnt, E);
    k_dinv <<<nbS, blk, 0, stream>>>(cnt, dinv, N);
    k_scan1<<<nbS, blk, 0, stream>>>(cnt, row_ptr, bsum, N);
    k_scan2<<<1, blk, 0, stream>>>(bsum, bpre, nbS);
    k_scan3<<<nbS, blk, 0, stream>>>(row_ptr, cursor, bpre, N, E);
    k_fill <<<(E + 255) / 256, blk, 0, stream>>>(ei, dinv, cursor, csr, E);

    constexpr int BM = 64;
    const int gblocks = (N + BM - 1) / BM;
    const int ablocks = (N + 3) / 4;

    // layer 1: h = x@W1 ; agg1 = relu(Â h + b1)
    k_gemm<C_HID, BM><<<gblocks, blk, 0, stream>>>(x, W1, h, N);
    k_agg128<true><<<ablocks, blk, 0, stream>>>(h, row_ptr, csr, dinv, b1, agg1, N);

    // layer 2: h2 = agg1@W2 ; out = Â h2 + b2
    k_gemm<C_OUT, BM><<<gblocks, blk, 0, stream>>>(agg1, W2, h2, N);
    k_agg64<false><<<ablocks, blk, 0, stream>>>(h2, row_ptr, csr, dinv, b2, out, N);
}

// Round 6
// 297.642 us; speedup vs baseline: 7.4132x; 1.0170x over previous
//
#include <hip/hip_runtime.h>

#define C_IN  128
#define C_HID 128
#define C_OUT 64

// ================= CSR build =================

__global__ __launch_bounds__(256) void k_count(const int* __restrict__ ei, int* __restrict__ cnt, int E) {
    int e = blockIdx.x * 256 + threadIdx.x;
    if (e < E) atomicAdd(&cnt[ei[E + e]], 1);  // dst
}

__global__ __launch_bounds__(256) void k_dinv(const int* __restrict__ cnt, float* __restrict__ dinv, int n) {
    int i = blockIdx.x * 256 + threadIdx.x;
    if (i < n) dinv[i] = rsqrtf((float)(cnt[i] + 1));  // +1 self-loop
}

__global__ __launch_bounds__(256) void k_scan1(const int* __restrict__ cnt, int* __restrict__ row_ptr,
                                               int* __restrict__ bsum, int n) {
    __shared__ int s[256];
    int tid = threadIdx.x;
    int i = blockIdx.x * 256 + tid;
    int v = (i < n) ? cnt[i] : 0;
    s[tid] = v;
    __syncthreads();
    #pragma unroll
    for (int off = 1; off < 256; off <<= 1) {
        int t = (tid >= off) ? s[tid - off] : 0;
        __syncthreads();
        s[tid] += t;
        __syncthreads();
    }
    if (i < n) row_ptr[i] = s[tid] - v;
    if (tid == 255) bsum[blockIdx.x] = s[255];
}

__global__ __launch_bounds__(256) void k_scan2(const int* __restrict__ bsum, int* __restrict__ bpre, int nb) {
    __shared__ int s[256];
    int tid = threadIdx.x;
    int v = (tid < nb) ? bsum[tid] : 0;
    s[tid] = v;
    __syncthreads();
    #pragma unroll
    for (int off = 1; off < 256; off <<= 1) {
        int t = (tid >= off) ? s[tid - off] : 0;
        __syncthreads();
        s[tid] += t;
        __syncthreads();
    }
    if (tid < nb) bpre[tid] = s[tid] - v;
}

__global__ __launch_bounds__(256) void k_scan3(int* __restrict__ row_ptr, int* __restrict__ cursor,
                                               const int* __restrict__ bpre, int n, int E) {
    int i = blockIdx.x * 256 + threadIdx.x;
    if (i < n) {
        int r = row_ptr[i] + bpre[blockIdx.x];
        row_ptr[i] = r;
        cursor[i] = r;
    }
    if (i == 0) row_ptr[n] = E;
}

__global__ __launch_bounds__(256) void k_fill(const int* __restrict__ ei, const float* __restrict__ dinv,
                                              int* __restrict__ cursor, int2* __restrict__ csr, int E) {
    int e = blockIdx.x * 256 + threadIdx.x;
    if (e >= E) return;
    int s = ei[e];
    int d = ei[E + e];
    int pos = atomicAdd(&cursor[d], 1);
    csr[pos] = make_int2(s, __float_as_int(dinv[s] * dinv[d]));
}

// ================= GEMM: H[M,N] = X[M,128] @ W[128,N] =================
// W staged in LDS in two k-halves (32KB for N=128) -> 4-5 blocks/CU occupancy.
// Lanes = output columns; rows wave-uniform -> X via s_load (SGPR operand).

template<int N, int BM>
__global__ __launch_bounds__(256) void k_gemm(const float* __restrict__ X,
                                              const float* __restrict__ W,
                                              float* __restrict__ H, int M) {
    constexpr int K = 128, KH = 64;
    constexpr int CPL = N / 64;          // cols per lane: 2 (N=128) or 1 (N=64)
    constexpr int R = 8;                 // rows per wave per chunk
    constexpr int CH = BM / (4 * R);     // chunks: 2 for BM=64
    __shared__ float sW[KH * N];         // 32KB (N=128) / 16KB (N=64)

    const int tid = threadIdx.x;
    const int wave = __builtin_amdgcn_readfirstlane(tid >> 6);
    const int lane = tid & 63;
    const int rowBase = blockIdx.x * BM;

    float acc[CH][R][CPL];
    #pragma unroll
    for (int ch = 0; ch < CH; ++ch)
        #pragma unroll
        for (int r = 0; r < R; ++r)
            #pragma unroll
            for (int u = 0; u < CPL; ++u) acc[ch][r][u] = 0.f;

    #pragma unroll
    for (int half = 0; half < 2; ++half) {
        if (half) __syncthreads();       // protect sW before overwrite
        {
            const float4* W4 = (const float4*)(W + half * KH * N);
            #pragma unroll
            for (int i = tid; i < KH * N / 4; i += 256) ((float4*)sW)[i] = W4[i];
        }
        __syncthreads();

        #pragma unroll
        for (int ch = 0; ch < CH; ++ch) {
            const int m0 = rowBase + ch * (4 * R) + wave * R;
            if (m0 >= M) continue;
            const float* Xb = X + (size_t)m0 * K + half * KH;

            if (m0 + R <= M) {
                #pragma unroll 2
                for (int k0 = 0; k0 < KH; k0 += 4) {
                    float4 xv[R];
                    #pragma unroll
                    for (int r = 0; r < R; ++r)
                        xv[r] = *(const float4*)(Xb + (size_t)r * K + k0);
                    #pragma unroll
                    for (int kk = 0; kk < 4; ++kk) {
                        float w0 = sW[(k0 + kk) * N + lane];
                        float w1 = (CPL == 2) ? sW[(k0 + kk) * N + 64 + lane] : 0.f;
                        #pragma unroll
                        for (int r = 0; r < R; ++r) {
                            float xr = (kk == 0) ? xv[r].x : (kk == 1) ? xv[r].y
                                     : (kk == 2) ? xv[r].z : xv[r].w;
                            acc[ch][r][0] += xr * w0;
                            if (CPL == 2) acc[ch][r][1] += xr * w1;
                        }
                    }
                }
            } else {
                for (int k0 = 0; k0 < KH; k0 += 4) {
                    float4 xv[R];
                    #pragma unroll
                    for (int r = 0; r < R; ++r) {
                        if (m0 + r < M) xv[r] = *(const float4*)(Xb + (size_t)r * K + k0);
                        else            xv[r] = make_float4(0.f, 0.f, 0.f, 0.f);
                    }
                    #pragma unroll
                    for (int kk = 0; kk < 4; ++kk) {
                        float w0 = sW[(k0 + kk) * N + lane];
                        float w1 = (CPL == 2) ? sW[(k0 + kk) * N + 64 + lane] : 0.f;
                        #pragma unroll
                        for (int r = 0; r < R; ++r) {
                            float xr = (kk == 0) ? xv[r].x : (kk == 1) ? xv[r].y
                                     : (kk == 2) ? xv[r].z : xv[r].w;
                            acc[ch][r][0] += xr * w0;
                            if (CPL == 2) acc[ch][r][1] += xr * w1;
                        }
                    }
                }
            }
        }
    }

    #pragma unroll
    for (int ch = 0; ch < CH; ++ch) {
        const int m0 = rowBase + ch * (4 * R) + wave * R;
        #pragma unroll
        for (int r = 0; r < R; ++r) {
            if (m0 + r < M) {
                H[(size_t)(m0 + r) * N + lane] = acc[ch][r][0];
                if (CPL == 2) H[(size_t)(m0 + r) * N + 64 + lane] = acc[ch][r][1];
            }
        }
    }
}

// ================= aggregation: wave owns G=4 consecutive nodes, streams combined
// edge range in U=16 batches. lane = fixed channels (R3/R5-proven mapping).
// Edge->node routing by wave-uniform interval test; coef zeroed past stream end.

template<int C, bool RELU>
__global__ __launch_bounds__(256) void k_agg(const float* __restrict__ h,
                                             const int* __restrict__ row_ptr,
                                             const int2* __restrict__ csr,
                                             const float* __restrict__ dinv,
                                             const float* __restrict__ bias,
                                             float* __restrict__ agg, int n) {
    constexpr int G = 4;                 // nodes per wave
    constexpr int U = 16;                // edges per batch (gathers in flight)
    constexpr int VPC = C / 64;          // floats per lane: 2 (C=128) or 1 (C=64)
    const int lane = threadIdx.x & 63;
    const int wv = __builtin_amdgcn_readfirstlane(threadIdx.x >> 6);
    const int v0 = (blockIdx.x * 4 + wv) * G;
    if (v0 >= n) return;

    int rp[G + 1];
    #pragma unroll
    for (int g = 0; g <= G; ++g) rp[g] = row_ptr[min(v0 + g, n)];

    float acc[G][VPC];
    #pragma unroll
    for (int g = 0; g < G; ++g) {
        #pragma unroll
        for (int u = 0; u < VPC; ++u) acc[g][u] = 0.f;
        if (v0 + g < n) {
            float di = dinv[v0 + g];
            float sl = di * di;
            if (VPC == 2) {
                float2 t = ((const float2*)h)[(size_t)(v0 + g) * 64 + lane];
                acc[g][0] = t.x * sl;
                acc[g][1] = t.y * sl;
            } else {
                acc[g][0] = h[(size_t)(v0 + g) * 64 + lane] * sl;
            }
        }
    }

    const int e = rp[G];
    for (int j0 = rp[0]; j0 < e; j0 += U) {
        int2 ee[U];
        #pragma unroll
        for (int u = 0; u < U; ++u) ee[u] = csr[j0 + u];  // contiguous scalar loads
                                                          // (<=120B overread into next ws buffer)
        float hv[U][VPC];
        #pragma unroll
        for (int u = 0; u < U; ++u) {
            int s = (j0 + u < e) ? ee[u].x : 0;           // clamp src for OOB slots
            if (VPC == 2) {
                float2 t = ((const float2*)h)[(size_t)s * 64 + lane];
                hv[u][0] = t.x;
                hv[u][1] = t.y;
            } else {
                hv[u][0] = h[(size_t)s * 64 + lane];
            }
        }
        #pragma unroll
        for (int u = 0; u < U; ++u) {
            const int jj = j0 + u;
            float c = (jj < e) ? __int_as_float(ee[u].y) : 0.f;
            #pragma unroll
            for (int g = 0; g < G; ++g) {
                bool in_g = (jj >= rp[g]) && (jj < rp[g + 1]);  // wave-uniform
                float cg = in_g ? c : 0.f;
                #pragma unroll
                for (int u2 = 0; u2 < VPC; ++u2) acc[g][u2] += cg * hv[u][u2];
            }
        }
    }

    #pragma unroll
    for (int g = 0; g < G; ++g) {
        if (v0 + g < n) {
            if (VPC == 2) {
                float2 bv = ((const float2*)bias)[lane];
                float2 o;
                o.x = acc[g][0] + bv.x;
                o.y = acc[g][1] + bv.y;
                if (RELU) { o.x = fmaxf(o.x, 0.f); o.y = fmaxf(o.y, 0.f); }
                ((float2*)agg)[(size_t)(v0 + g) * 64 + lane] = o;
            } else {
                float o = acc[g][0] + bias[lane];
                if (RELU) o = fmaxf(o, 0.f);
                agg[(size_t)(v0 + g) * 64 + lane] = o;
            }
        }
    }
}

// ================= launch =================

extern "C" void kernel_launch(void* const* d_in, const int* in_sizes, int n_in,
                              void* d_out, int out_size, void* d_ws, size_t ws_size,
                              hipStream_t stream) {
    const float* x  = (const float*)d_in[0];
    const int*   ei = (const int*)d_in[1];
    const float* W1 = (const float*)d_in[2];
    const float* b1 = (const float*)d_in[3];
    const float* W2 = (const float*)d_in[4];
    const float* b2 = (const float*)d_in[5];
    float* out = (float*)d_out;

    const int N = in_sizes[0] / C_IN;   // 50000
    const int E = in_sizes[1] / 2;      // 800000

    // 16B-aligned workspace layout
    char* base = (char*)d_ws;
    size_t off = 0;
    auto alloc = [&](size_t bytes) {
        char* q = base + off;
        off = (off + bytes + 15) & ~(size_t)15;
        return q;
    };
    int*   cnt      = (int*)  alloc((size_t)N * 4);
    float* dinv     = (float*)alloc((size_t)N * 4);
    int*   row_ptr  = (int*)  alloc((size_t)(N + 1) * 4);
    int*   cursor   = (int*)  alloc((size_t)N * 4);
    int*   bsum     = (int*)  alloc(256 * 4);
    int*   bpre     = (int*)  alloc(256 * 4);
    int2*  csr      = (int2*) alloc((size_t)E * 8);
    float* h        = (float*)alloc((size_t)N * C_HID * 4);
    float* agg1     = (float*)alloc((size_t)N * C_HID * 4);
    float* h2       = h;  // reuse: layer-1 h dead once agg1 complete

    dim3 blk(256);
    const int nbS = (N + 255) / 256;

    hipMemsetAsync(cnt, 0, (size_t)N * 4, stream);
    k_count<<<(E + 255) / 256, blk, 0, stream>>>(ei, cnt, E);
    k_dinv <<<nbS, blk, 0, stream>>>(cnt, dinv, N);
    k_scan1<<<nbS, blk, 0, stream>>>(cnt, row_ptr, bsum, N);
    k_scan2<<<1, blk, 0, stream>>>(bsum, bpre, nbS);
    k_scan3<<<nbS, blk, 0, stream>>>(row_ptr, cursor, bpre, N, E);
    k_fill <<<(E + 255) / 256, blk, 0, stream>>>(ei, dinv, cursor, csr, E);

    constexpr int BM = 64;
    const int gblocks = (N + BM - 1) / BM;
    const int ablocks = (N + 15) / 16;   // 4 waves x G=4 nodes per block

    // layer 1: h = x@W1 ; agg1 = relu(Â h + b1)
    k_gemm<C_HID, BM><<<gblocks, blk, 0, stream>>>(x, W1, h, N);
    k_agg<C_HID, true><<<ablocks, blk, 0, stream>>>(h, row_ptr, csr, dinv, b1, agg1, N);

    // layer 2: h2 = agg1@W2 ; out = Â h2 + b2
    k_gemm<C_OUT, BM><<<gblocks, blk, 0, stream>>>(agg1, W2, h2, N);
    k_agg<C_OUT, false><<<ablocks, blk, 0, stream>>>(h2, row_ptr, csr, dinv, b2, out, N);
}

// Round 7
// 271.200 us; speedup vs baseline: 8.1359x; 1.0975x over previous
//
#include <hip/hip_runtime.h>

#define C_IN  128
#define C_HID 128
#define C_OUT 64

// bf16 helpers (RNE)
__device__ __forceinline__ unsigned f2bf(float f) {
    unsigned u = __float_as_uint(f);
    return (u + 0x7FFF + ((u >> 16) & 1)) >> 16;
}
__device__ __forceinline__ float bflo(unsigned t) { return __uint_as_float(t << 16); }
__device__ __forceinline__ float bfhi(unsigned t) { return __uint_as_float(t & 0xFFFF0000u); }

// ================= CSR build =================

__global__ __launch_bounds__(256) void k_count(const int* __restrict__ ei, int* __restrict__ cnt, int E) {
    int e = blockIdx.x * 256 + threadIdx.x;
    if (e < E) atomicAdd(&cnt[ei[E + e]], 1);  // dst
}

__global__ __launch_bounds__(256) void k_dinv(const int* __restrict__ cnt, float* __restrict__ dinv, int n) {
    int i = blockIdx.x * 256 + threadIdx.x;
    if (i < n) dinv[i] = rsqrtf((float)(cnt[i] + 1));  // +1 self-loop
}

__global__ __launch_bounds__(256) void k_scan1(const int* __restrict__ cnt, int* __restrict__ row_ptr,
                                               int* __restrict__ bsum, int n) {
    __shared__ int s[256];
    int tid = threadIdx.x;
    int i = blockIdx.x * 256 + tid;
    int v = (i < n) ? cnt[i] : 0;
    s[tid] = v;
    __syncthreads();
    #pragma unroll
    for (int off = 1; off < 256; off <<= 1) {
        int t = (tid >= off) ? s[tid - off] : 0;
        __syncthreads();
        s[tid] += t;
        __syncthreads();
    }
    if (i < n) row_ptr[i] = s[tid] - v;
    if (tid == 255) bsum[blockIdx.x] = s[255];
}

__global__ __launch_bounds__(256) void k_scan2(const int* __restrict__ bsum, int* __restrict__ bpre, int nb) {
    __shared__ int s[256];
    int tid = threadIdx.x;
    int v = (tid < nb) ? bsum[tid] : 0;
    s[tid] = v;
    __syncthreads();
    #pragma unroll
    for (int off = 1; off < 256; off <<= 1) {
        int t = (tid >= off) ? s[tid - off] : 0;
        __syncthreads();
        s[tid] += t;
        __syncthreads();
    }
    if (tid < nb) bpre[tid] = s[tid] - v;
}

__global__ __launch_bounds__(256) void k_scan3(int* __restrict__ row_ptr, int* __restrict__ cursor,
                                               const int* __restrict__ bpre, int n, int E) {
    int i = blockIdx.x * 256 + threadIdx.x;
    if (i < n) {
        int r = row_ptr[i] + bpre[blockIdx.x];
        row_ptr[i] = r;
        cursor[i] = r;
    }
    if (i == 0) row_ptr[n] = E;
}

__global__ __launch_bounds__(256) void k_fill(const int* __restrict__ ei, const float* __restrict__ dinv,
                                              int* __restrict__ cursor, int2* __restrict__ csr, int E) {
    int e = blockIdx.x * 256 + threadIdx.x;
    if (e >= E) return;
    int s = ei[e];
    int d = ei[E + e];
    int pos = atomicAdd(&cursor[d], 1);
    csr[pos] = make_int2(s, __float_as_int(dinv[s] * dinv[d]));
}

// ================= GEMM: Hbf16[M,N] = X[M,128] @ W[128,N] =================
// W staged in LDS in two k-halves; lanes = output cols; rows wave-uniform (X via s_load).
// N=128: lane owns col pair (2l, 2l+1), packs one uint of 2 bf16.
// N=64 : lane owns col l, stores one ushort.

template<int N, int BM>
__global__ __launch_bounds__(256) void k_gemm(const float* __restrict__ X,
                                              const float* __restrict__ W,
                                              void* __restrict__ Hout, int M) {
    constexpr int K = 128, KH = 64;
    constexpr int CPL = N / 64;          // 2 (N=128) or 1 (N=64)
    constexpr int R = 8;
    constexpr int CH = BM / (4 * R);     // 2 for BM=64
    __shared__ float sW[KH * N];         // 32KB (N=128) / 16KB (N=64)

    const int tid = threadIdx.x;
    const int wave = __builtin_amdgcn_readfirstlane(tid >> 6);
    const int lane = tid & 63;
    const int rowBase = blockIdx.x * BM;

    float acc[CH][R][CPL];
    #pragma unroll
    for (int ch = 0; ch < CH; ++ch)
        #pragma unroll
        for (int r = 0; r < R; ++r)
            #pragma unroll
            for (int u = 0; u < CPL; ++u) acc[ch][r][u] = 0.f;

    #pragma unroll
    for (int half = 0; half < 2; ++half) {
        if (half) __syncthreads();
        {
            const float4* W4 = (const float4*)(W + half * KH * N);
            #pragma unroll
            for (int i = tid; i < KH * N / 4; i += 256) ((float4*)sW)[i] = W4[i];
        }
        __syncthreads();

        #pragma unroll
        for (int ch = 0; ch < CH; ++ch) {
            const int m0 = rowBase + ch * (4 * R) + wave * R;
            if (m0 >= M) continue;
            const float* Xb = X + (size_t)m0 * K + half * KH;

            if (m0 + R <= M) {
                #pragma unroll 2
                for (int k0 = 0; k0 < KH; k0 += 4) {
                    float4 xv[R];
                    #pragma unroll
                    for (int r = 0; r < R; ++r)
                        xv[r] = *(const float4*)(Xb + (size_t)r * K + k0);
                    #pragma unroll
                    for (int kk = 0; kk < 4; ++kk) {
                        float w0, w1;
                        if (CPL == 2) {
                            float2 wv = *(const float2*)&sW[(k0 + kk) * N + 2 * lane];
                            w0 = wv.x; w1 = wv.y;
                        } else {
                            w0 = sW[(k0 + kk) * N + lane]; w1 = 0.f;
                        }
                        #pragma unroll
                        for (int r = 0; r < R; ++r) {
                            float xr = (kk == 0) ? xv[r].x : (kk == 1) ? xv[r].y
                                     : (kk == 2) ? xv[r].z : xv[r].w;
                            acc[ch][r][0] += xr * w0;
                            if (CPL == 2) acc[ch][r][1] += xr * w1;
                        }
                    }
                }
            } else {
                for (int k0 = 0; k0 < KH; k0 += 4) {
                    float4 xv[R];
                    #pragma unroll
                    for (int r = 0; r < R; ++r) {
                        if (m0 + r < M) xv[r] = *(const float4*)(Xb + (size_t)r * K + k0);
                        else            xv[r] = make_float4(0.f, 0.f, 0.f, 0.f);
                    }
                    #pragma unroll
                    for (int kk = 0; kk < 4; ++kk) {
                        float w0, w1;
                        if (CPL == 2) {
                            float2 wv = *(const float2*)&sW[(k0 + kk) * N + 2 * lane];
                            w0 = wv.x; w1 = wv.y;
                        } else {
                            w0 = sW[(k0 + kk) * N + lane]; w1 = 0.f;
                        }
                        #pragma unroll
                        for (int r = 0; r < R; ++r) {
                            float xr = (kk == 0) ? xv[r].x : (kk == 1) ? xv[r].y
                                     : (kk == 2) ? xv[r].z : xv[r].w;
                            acc[ch][r][0] += xr * w0;
                            if (CPL == 2) acc[ch][r][1] += xr * w1;
                        }
                    }
                }
            }
        }
    }

    #pragma unroll
    for (int ch = 0; ch < CH; ++ch) {
        const int m0 = rowBase + ch * (4 * R) + wave * R;
        #pragma unroll
        for (int r = 0; r < R; ++r) {
            if (m0 + r < M) {
                if (CPL == 2) {
                    unsigned p = (f2bf(acc[ch][r][1]) << 16) | f2bf(acc[ch][r][0]);
                    ((unsigned*)Hout)[(size_t)(m0 + r) * 64 + lane] = p;
                } else {
                    ((unsigned short*)Hout)[(size_t)(m0 + r) * 64 + lane] =
                        (unsigned short)f2bf(acc[ch][r][0]);
                }
            }
        }
    }
}

// ================= aggregation over bf16 h: wave owns G=4 nodes, U=16 edge batches =================
// C=128: lane owns cols (2l,2l+1): one uint gather/lane. C=64: lane owns col l: ushort gather.
// agg (f32) = f( h[v]*dinv^2 + sum coef*h[s] + bias )

template<int C, bool RELU>
__global__ __launch_bounds__(256) void k_agg(const void* __restrict__ hraw,
                                             const int* __restrict__ row_ptr,
                                             const int2* __restrict__ csr,
                                             const float* __restrict__ dinv,
                                             const float* __restrict__ bias,
                                             float* __restrict__ agg, int n) {
    constexpr int G = 4;
    constexpr int U = 16;
    constexpr int VPC = C / 64;          // 2 (C=128) or 1 (C=64)
    const int lane = threadIdx.x & 63;
    const int wv = __builtin_amdgcn_readfirstlane(threadIdx.x >> 6);
    const int v0 = (blockIdx.x * 4 + wv) * G;
    if (v0 >= n) return;

    const unsigned*       hu = (const unsigned*)hraw;        // C=128 view
    const unsigned short* hs = (const unsigned short*)hraw;  // C=64 view

    int rp[G + 1];
    #pragma unroll
    for (int g = 0; g <= G; ++g) rp[g] = row_ptr[min(v0 + g, n)];

    float acc[G][VPC];
    #pragma unroll
    for (int g = 0; g < G; ++g) {
        #pragma unroll
        for (int u = 0; u < VPC; ++u) acc[g][u] = 0.f;
        if (v0 + g < n) {
            float di = dinv[v0 + g];
            float sl = di * di;
            if (VPC == 2) {
                unsigned t = hu[(size_t)(v0 + g) * 64 + lane];
                acc[g][0] = bflo(t) * sl;
                acc[g][1] = bfhi(t) * sl;
            } else {
                acc[g][0] = bflo(hs[(size_t)(v0 + g) * 64 + lane]) * sl;
            }
        }
    }

    const int e = rp[G];
    for (int j0 = rp[0]; j0 < e; j0 += U) {
        int2 ee[U];
        #pragma unroll
        for (int u = 0; u < U; ++u) ee[u] = csr[j0 + u];  // contiguous scalar loads
                                                          // (<=120B overread into next ws buffer)
        float hv[U][VPC];
        #pragma unroll
        for (int u = 0; u < U; ++u) {
            int s = (j0 + u < e) ? ee[u].x : 0;           // clamp src for OOB slots
            if (VPC == 2) {
                unsigned t = hu[(size_t)s * 64 + lane];
                hv[u][0] = bflo(t);
                hv[u][1] = bfhi(t);
            } else {
                hv[u][0] = bflo(hs[(size_t)s * 64 + lane]);
            }
        }
        #pragma unroll
        for (int u = 0; u < U; ++u) {
            const int jj = j0 + u;
            float c = (jj < e) ? __int_as_float(ee[u].y) : 0.f;
            #pragma unroll
            for (int g = 0; g < G; ++g) {
                bool in_g = (jj >= rp[g]) && (jj < rp[g + 1]);  // wave-uniform
                float cg = in_g ? c : 0.f;
                #pragma unroll
                for (int u2 = 0; u2 < VPC; ++u2) acc[g][u2] += cg * hv[u][u2];
            }
        }
    }

    #pragma unroll
    for (int g = 0; g < G; ++g) {
        if (v0 + g < n) {
            if (VPC == 2) {
                float2 bv = ((const float2*)bias)[lane];   // bias[2l], bias[2l+1]
                float2 o;
                o.x = acc[g][0] + bv.x;
                o.y = acc[g][1] + bv.y;
                if (RELU) { o.x = fmaxf(o.x, 0.f); o.y = fmaxf(o.y, 0.f); }
                ((float2*)agg)[(size_t)(v0 + g) * 64 + lane] = o;  // cols 2l,2l+1
            } else {
                float o = acc[g][0] + bias[lane];
                if (RELU) o = fmaxf(o, 0.f);
                agg[(size_t)(v0 + g) * 64 + lane] = o;
            }
        }
    }
}

// ================= launch =================

extern "C" void kernel_launch(void* const* d_in, const int* in_sizes, int n_in,
                              void* d_out, int out_size, void* d_ws, size_t ws_size,
                              hipStream_t stream) {
    const float* x  = (const float*)d_in[0];
    const int*   ei = (const int*)d_in[1];
    const float* W1 = (const float*)d_in[2];
    const float* b1 = (const float*)d_in[3];
    const float* W2 = (const float*)d_in[4];
    const float* b2 = (const float*)d_in[5];
    float* out = (float*)d_out;

    const int N = in_sizes[0] / C_IN;   // 50000
    const int E = in_sizes[1] / 2;      // 800000

    // 16B-aligned workspace layout
    char* base = (char*)d_ws;
    size_t off = 0;
    auto alloc = [&](size_t bytes) {
        char* q = base + off;
        off = (off + bytes + 15) & ~(size_t)15;
        return q;
    };
    int*   cnt      = (int*)  alloc((size_t)N * 4);
    float* dinv     = (float*)alloc((size_t)N * 4);
    int*   row_ptr  = (int*)  alloc((size_t)(N + 1) * 4);
    int*   cursor   = (int*)  alloc((size_t)N * 4);
    int*   bsum     = (int*)  alloc(256 * 4);
    int*   bpre     = (int*)  alloc(256 * 4);
    int2*  csr      = (int2*) alloc((size_t)E * 8);
    void*  h        = (void*) alloc((size_t)N * C_HID * 2);   // bf16 h (layer 1)
    float* agg1     = (float*)alloc((size_t)N * C_HID * 4);   // f32
    void*  h2       = h;  // bf16 h2 (layer 2) reuses h (dead after agg128)

    dim3 blk(256);
    const int nbS = (N + 255) / 256;

    hipMemsetAsync(cnt, 0, (size_t)N * 4, stream);
    k_count<<<(E + 255) / 256, blk, 0, stream>>>(ei, cnt, E);
    k_dinv <<<nbS, blk, 0, stream>>>(cnt, dinv, N);
    k_scan1<<<nbS, blk, 0, stream>>>(cnt, row_ptr, bsum, N);
    k_scan2<<<1, blk, 0, stream>>>(bsum, bpre, nbS);
    k_scan3<<<nbS, blk, 0, stream>>>(row_ptr, cursor, bpre, N, E);
    k_fill <<<(E + 255) / 256, blk, 0, stream>>>(ei, dinv, cursor, csr, E);

    constexpr int BM = 64;
    const int gblocks = (N + BM - 1) / BM;
    const int ablocks = (N + 15) / 16;   // 4 waves x G=4 nodes per block

    // layer 1: h = bf16(x@W1) ; agg1 = relu(Â h + b1)
    k_gemm<C_HID, BM><<<gblocks, blk, 0, stream>>>(x, W1, h, N);
    k_agg<C_HID, true><<<ablocks, blk, 0, stream>>>(h, row_ptr, csr, dinv, b1, agg1, N);

    // layer 2: h2 = bf16(agg1@W2) ; out = Â h2 + b2
    k_gemm<C_OUT, BM><<<gblocks, blk, 0, stream>>>(agg1, W2, h2, N);
    k_agg<C_OUT, false><<<ablocks, blk, 0, stream>>>(h2, row_ptr, csr, dinv, b2, out, N);
}

// Round 8
// 209.943 us; speedup vs baseline: 10.5098x; 1.2918x over previous
//
#include <hip/hip_runtime.h>

#define C_IN  128
#define C_HID 128
#define C_OUT 64

typedef __attribute__((ext_vector_type(8))) short short8;
typedef __attribute__((ext_vector_type(4))) float f32x4;

// bf16 helpers (RNE)
__device__ __forceinline__ unsigned f2bf(float f) {
    unsigned u = __float_as_uint(f);
    return (u + 0x7FFF + ((u >> 16) & 1)) >> 16;
}
__device__ __forceinline__ float bflo(unsigned t) { return __uint_as_float(t << 16); }
__device__ __forceinline__ float bfhi(unsigned t) { return __uint_as_float(t & 0xFFFF0000u); }

// ================= x f32 -> bf16 (packed) =================

__global__ __launch_bounds__(256) void k_cvt(const float4* __restrict__ in, uint2* __restrict__ outp, int n4) {
    int i = blockIdx.x * 256 + threadIdx.x;
    if (i < n4) {
        float4 v = in[i];
        uint2 o;
        o.x = (f2bf(v.y) << 16) | f2bf(v.x);
        o.y = (f2bf(v.w) << 16) | f2bf(v.z);
        outp[i] = o;
    }
}

// ================= CSR build =================

__global__ __launch_bounds__(256) void k_count(const int* __restrict__ ei, int* __restrict__ cnt, int E) {
    int e = blockIdx.x * 256 + threadIdx.x;
    if (e < E) atomicAdd(&cnt[ei[E + e]], 1);  // dst
}

__global__ __launch_bounds__(256) void k_dinv(const int* __restrict__ cnt, float* __restrict__ dinv, int n) {
    int i = blockIdx.x * 256 + threadIdx.x;
    if (i < n) dinv[i] = rsqrtf((float)(cnt[i] + 1));  // +1 self-loop
}

__global__ __launch_bounds__(256) void k_scan1(const int* __restrict__ cnt, int* __restrict__ row_ptr,
                                               int* __restrict__ bsum, int n) {
    __shared__ int s[256];
    int tid = threadIdx.x;
    int i = blockIdx.x * 256 + tid;
    int v = (i < n) ? cnt[i] : 0;
    s[tid] = v;
    __syncthreads();
    #pragma unroll
    for (int off = 1; off < 256; off <<= 1) {
        int t = (tid >= off) ? s[tid - off] : 0;
        __syncthreads();
        s[tid] += t;
        __syncthreads();
    }
    if (i < n) row_ptr[i] = s[tid] - v;
    if (tid == 255) bsum[blockIdx.x] = s[255];
}

__global__ __launch_bounds__(256) void k_scan2(const int* __restrict__ bsum, int* __restrict__ bpre, int nb) {
    __shared__ int s[256];
    int tid = threadIdx.x;
    int v = (tid < nb) ? bsum[tid] : 0;
    s[tid] = v;
    __syncthreads();
    #pragma unroll
    for (int off = 1; off < 256; off <<= 1) {
        int t = (tid >= off) ? s[tid - off] : 0;
        __syncthreads();
        s[tid] += t;
        __syncthreads();
    }
    if (tid < nb) bpre[tid] = s[tid] - v;
}

__global__ __launch_bounds__(256) void k_scan3(int* __restrict__ row_ptr, int* __restrict__ cursor,
                                               const int* __restrict__ bpre, int n, int E) {
    int i = blockIdx.x * 256 + threadIdx.x;
    if (i < n) {
        int r = row_ptr[i] + bpre[blockIdx.x];
        row_ptr[i] = r;
        cursor[i] = r;
    }
    if (i == 0) row_ptr[n] = E;
}

__global__ __launch_bounds__(256) void k_fill(const int* __restrict__ ei, const float* __restrict__ dinv,
                                              int* __restrict__ cursor, int2* __restrict__ csr, int E) {
    int e = blockIdx.x * 256 + threadIdx.x;
    if (e >= E) return;
    int s = ei[e];
    int d = ei[E + e];
    int pos = atomicAdd(&cursor[d], 1);
    csr[pos] = make_int2(s, __float_as_int(dinv[s] * dinv[d]));
}

// ================= MFMA GEMM: Hbf16[M,N] = Xbf16[M,128] @ Wf32[128,N] =================
// 256 thr = 4 waves; wave w owns 16-row strip (M % 16 == 0). mfma_f32_16x16x32_bf16.
// A frag: row=lane&15, k=(lane>>4)*8+j (from global bf16 rows).
// B frag: col=lane&15, same k formula (from LDS, W transposed [N][K+8] bf16).
// A/B use identical lane->k maps, so any hw k-permutation cancels.
// C/D: col=lane&15, row=(lane>>4)*4+reg (m89-verified).

template<int N>
__global__ __launch_bounds__(256) void k_gemm_mfma(const unsigned short* __restrict__ X,
                                                   const float* __restrict__ W,
                                                   unsigned short* __restrict__ H, int M) {
    constexpr int K = 128;
    constexpr int LDT = K + 8;                 // pad: 2-way-free b128 reads
    __shared__ unsigned short sWt[N * LDT];

    const int tid = threadIdx.x;
    // stage W transposed as bf16 (coalesced f32 reads)
    constexpr int NLOG = (N == 128) ? 7 : 6;
    for (int idx = tid; idx < K * N; idx += 256) {
        int k = idx >> NLOG, c = idx & (N - 1);
        sWt[c * LDT + k] = (unsigned short)f2bf(W[idx]);
    }
    __syncthreads();

    const int wave = __builtin_amdgcn_readfirstlane(tid >> 6);
    const int lane = tid & 63;
    const int m0 = blockIdx.x * 64 + wave * 16;
    if (m0 >= M) return;                        // no syncthreads after this point

    const int arow = lane & 15;
    const int koff = (lane >> 4) * 8;

    // A fragments: 16B each, k0 = 0,32,64,96
    const unsigned short* ap = X + (size_t)(m0 + arow) * K + koff;
    short8 a[4];
    #pragma unroll
    for (int q = 0; q < 4; ++q) a[q] = *(const short8*)(ap + q * 32);

    #pragma unroll
    for (int ct = 0; ct < N / 16; ++ct) {
        const int bcol = ct * 16 + (lane & 15);
        const unsigned short* bp = &sWt[bcol * LDT + koff];
        f32x4 acc = {0.f, 0.f, 0.f, 0.f};
        #pragma unroll
        for (int q = 0; q < 4; ++q) {
            short8 b = *(const short8*)(bp + q * 32);
            acc = __builtin_amdgcn_mfma_f32_16x16x32_bf16(a[q], b, acc, 0, 0, 0);
        }
        const int row0 = m0 + (lane >> 4) * 4;
        const int col = ct * 16 + (lane & 15);
        #pragma unroll
        for (int r = 0; r < 4; ++r)
            H[(size_t)(row0 + r) * N + col] = (unsigned short)f2bf(acc[r]);
    }
}

// ================= aggregation over bf16 h: wave owns G=4 nodes, U=16 edge batches =================
// C=128: lane owns cols (2l,2l+1): one uint gather/lane. C=64: lane owns col l: ushort gather.
// OUTBF: store packed bf16 (feeds next MFMA GEMM); else f32.

template<int C, bool RELU, bool OUTBF>
__global__ __launch_bounds__(256) void k_agg(const void* __restrict__ hraw,
                                             const int* __restrict__ row_ptr,
                                             const int2* __restrict__ csr,
                                             const float* __restrict__ dinv,
                                             const float* __restrict__ bias,
                                             void* __restrict__ agg, int n) {
    constexpr int G = 4;
    constexpr int U = 16;
    constexpr int VPC = C / 64;          // 2 (C=128) or 1 (C=64)
    const int lane = threadIdx.x & 63;
    const int wv = __builtin_amdgcn_readfirstlane(threadIdx.x >> 6);
    const int v0 = (blockIdx.x * 4 + wv) * G;
    if (v0 >= n) return;

    const unsigned*       hu = (const unsigned*)hraw;        // C=128 view
    const unsigned short* hs = (const unsigned short*)hraw;  // C=64 view

    int rp[G + 1];
    #pragma unroll
    for (int g = 0; g <= G; ++g) rp[g] = row_ptr[min(v0 + g, n)];

    float acc[G][VPC];
    #pragma unroll
    for (int g = 0; g < G; ++g) {
        #pragma unroll
        for (int u = 0; u < VPC; ++u) acc[g][u] = 0.f;
        if (v0 + g < n) {
            float di = dinv[v0 + g];
            float sl = di * di;
            if (VPC == 2) {
                unsigned t = hu[(size_t)(v0 + g) * 64 + lane];
                acc[g][0] = bflo(t) * sl;
                acc[g][1] = bfhi(t) * sl;
            } else {
                acc[g][0] = bflo(hs[(size_t)(v0 + g) * 64 + lane]) * sl;
            }
        }
    }

    const int e = rp[G];
    for (int j0 = rp[0]; j0 < e; j0 += U) {
        int2 ee[U];
        #pragma unroll
        for (int u = 0; u < U; ++u) ee[u] = csr[j0 + u];  // contiguous scalar loads
                                                          // (<=120B overread into next ws buffer)
        float hv[U][VPC];
        #pragma unroll
        for (int u = 0; u < U; ++u) {
            int s = (j0 + u < e) ? ee[u].x : 0;           // clamp src for OOB slots
            if (VPC == 2) {
                unsigned t = hu[(size_t)s * 64 + lane];
                hv[u][0] = bflo(t);
                hv[u][1] = bfhi(t);
            } else {
                hv[u][0] = bflo(hs[(size_t)s * 64 + lane]);
            }
        }
        #pragma unroll
        for (int u = 0; u < U; ++u) {
            const int jj = j0 + u;
            float c = (jj < e) ? __int_as_float(ee[u].y) : 0.f;
            #pragma unroll
            for (int g = 0; g < G; ++g) {
                bool in_g = (jj >= rp[g]) && (jj < rp[g + 1]);  // wave-uniform
                float cg = in_g ? c : 0.f;
                #pragma unroll
                for (int u2 = 0; u2 < VPC; ++u2) acc[g][u2] += cg * hv[u][u2];
            }
        }
    }

    #pragma unroll
    for (int g = 0; g < G; ++g) {
        if (v0 + g < n) {
            if (VPC == 2) {
                float2 bv = ((const float2*)bias)[lane];   // bias[2l], bias[2l+1]
                float ox = acc[g][0] + bv.x;
                float oy = acc[g][1] + bv.y;
                if (RELU) { ox = fmaxf(ox, 0.f); oy = fmaxf(oy, 0.f); }
                if (OUTBF) {
                    ((unsigned*)agg)[(size_t)(v0 + g) * 64 + lane] = (f2bf(oy) << 16) | f2bf(ox);
                } else {
                    ((float2*)agg)[(size_t)(v0 + g) * 64 + lane] = make_float2(ox, oy);
                }
            } else {
                float o = acc[g][0] + bias[lane];
                if (RELU) o = fmaxf(o, 0.f);
                if (OUTBF) ((unsigned short*)agg)[(size_t)(v0 + g) * 64 + lane] = (unsigned short)f2bf(o);
                else       ((float*)agg)[(size_t)(v0 + g) * 64 + lane] = o;
            }
        }
    }
}

// ================= launch =================

extern "C" void kernel_launch(void* const* d_in, const int* in_sizes, int n_in,
                              void* d_out, int out_size, void* d_ws, size_t ws_size,
                              hipStream_t stream) {
    const float* x  = (const float*)d_in[0];
    const int*   ei = (const int*)d_in[1];
    const float* W1 = (const float*)d_in[2];
    const float* b1 = (const float*)d_in[3];
    const float* W2 = (const float*)d_in[4];
    const float* b2 = (const float*)d_in[5];
    float* out = (float*)d_out;

    const int N = in_sizes[0] / C_IN;   // 50000
    const int E = in_sizes[1] / 2;      // 800000

    // 16B-aligned workspace layout
    char* base = (char*)d_ws;
    size_t off = 0;
    auto alloc = [&](size_t bytes) {
        char* q = base + off;
        off = (off + bytes + 15) & ~(size_t)15;
        return q;
    };
    int*   cnt      = (int*)  alloc((size_t)N * 4);
    float* dinv     = (float*)alloc((size_t)N * 4);
    int*   row_ptr  = (int*)  alloc((size_t)(N + 1) * 4);
    int*   cursor   = (int*)  alloc((size_t)N * 4);
    int*   bsum     = (int*)  alloc(256 * 4);
    int*   bpre     = (int*)  alloc(256 * 4);
    int2*  csr      = (int2*) alloc((size_t)E * 8);
    unsigned short* xb   = (unsigned short*)alloc((size_t)N * C_IN * 2);   // bf16 x
    unsigned short* h    = (unsigned short*)alloc((size_t)N * C_HID * 2);  // bf16 h / h2
    unsigned short* agg1 = (unsigned short*)alloc((size_t)N * C_HID * 2);  // bf16 agg1
    unsigned short* h2   = h;  // layer-2 h reuses h (dead after agg128)

    dim3 blk(256);
    const int nbS = (N + 255) / 256;

    k_cvt  <<<((N * C_IN / 4) + 255) / 256, blk, 0, stream>>>((const float4*)x, (uint2*)xb, N * C_IN / 4);

    hipMemsetAsync(cnt, 0, (size_t)N * 4, stream);
    k_count<<<(E + 255) / 256, blk, 0, stream>>>(ei, cnt, E);
    k_dinv <<<nbS, blk, 0, stream>>>(cnt, dinv, N);
    k_scan1<<<nbS, blk, 0, stream>>>(cnt, row_ptr, bsum, N);
    k_scan2<<<1, blk, 0, stream>>>(bsum, bpre, nbS);
    k_scan3<<<nbS, blk, 0, stream>>>(row_ptr, cursor, bpre, N, E);
    k_fill <<<(E + 255) / 256, blk, 0, stream>>>(ei, dinv, cursor, csr, E);

    const int gblocks = (N + 63) / 64;
    const int ablocks = (N + 15) / 16;   // 4 waves x G=4 nodes per block

    // layer 1: h = bf16(xb @ W1) ; agg1 = bf16(relu(Â h + b1))
    k_gemm_mfma<C_HID><<<gblocks, blk, 0, stream>>>(xb, W1, h, N);
    k_agg<C_HID, true, true><<<ablocks, blk, 0, stream>>>(h, row_ptr, csr, dinv, b1, agg1, N);

    // layer 2: h2 = bf16(agg1 @ W2) ; out = Â h2 + b2
    k_gemm_mfma<C_OUT><<<gblocks, blk, 0, stream>>>(agg1, W2, h2, N);
    k_agg<C_OUT, false, false><<<ablocks, blk, 0, stream>>>(h2, row_ptr, csr, dinv, b2, out, N);
}